// Round 1
// baseline (843.846 us; speedup 1.0000x reference)
//
#include <hip/hip_runtime.h>

// LinkPredictorBackbone: GCN backbone, N=100000 nodes, E=1600000 edges, C=128.
// Pipeline per launch:
//   1. detect edge_index dtype (int64 vs int32), convert to int32 src/dst + in-degree counts
//   2. dinv[v] = rsqrt(count+1)  (self-loop included)
//   3. exclusive scan of counts -> CSR rowptr (+cursor copy)
//   4. fill CSR col array (atomic cursor)
//   5. h = relu(x @ W0 + b0)
//   6. 3x { hw = dinv * (h @ Wl) ; h = relu(BN(dinv*(hw[v]+sum hw[col]) + conv_b)) }
//   7. out = h @ W4 + b4

#define HIDC 128
#define BN_EPS 1e-5f
#define TM 64

// ---------------- graph build kernels ----------------

__global__ void detect64(const unsigned int* ei, int* flag) {
    if (threadIdx.x != 0 || blockIdx.x != 0) return;
    int is64 = 1;
    for (int i = 0; i < 64; ++i) {
        if (ei[2 * i + 1] != 0u) { is64 = 0; break; }
    }
    *flag = is64;
}

__global__ void convert_count(const void* __restrict__ ei, const int* __restrict__ flag,
                              int* __restrict__ src, int* __restrict__ dst,
                              int* __restrict__ counts, int e) {
    int i = blockIdx.x * 256 + threadIdx.x;
    if (i >= e) return;
    int s, d;
    if (*flag) {
        const long long* p = (const long long*)ei;
        s = (int)p[i];
        d = (int)p[e + i];
    } else {
        const int* p = (const int*)ei;
        s = p[i];
        d = p[e + i];
    }
    src[i] = s;
    dst[i] = d;
    atomicAdd(&counts[d], 1);
}

__global__ void compute_dinv(const int* __restrict__ counts, float* __restrict__ dinv, int n) {
    int i = blockIdx.x * 256 + threadIdx.x;
    if (i >= n) return;
    dinv[i] = rsqrtf((float)(counts[i] + 1));   // +1: self loop; deg >= 1 always
}

// scan: CHUNK=1024 per block (256 threads x 4)
__global__ void scan_block_totals(const int* __restrict__ counts, int* __restrict__ bsums, int n) {
    __shared__ int sdata[256];
    int t = threadIdx.x;
    int base = blockIdx.x * 1024 + t * 4;
    int s = 0;
#pragma unroll
    for (int i = 0; i < 4; ++i) {
        int idx = base + i;
        if (idx < n) s += counts[idx];
    }
    sdata[t] = s;
    __syncthreads();
    for (int off = 128; off > 0; off >>= 1) {
        if (t < off) sdata[t] += sdata[t + off];
        __syncthreads();
    }
    if (t == 0) bsums[blockIdx.x] = sdata[0];
}

__global__ void scan_bsums(int* bsums, int nb, int* rowptr, int n, int e) {
    if (threadIdx.x != 0 || blockIdx.x != 0) return;
    int run = 0;
    for (int i = 0; i < nb; ++i) {
        int v = bsums[i];
        bsums[i] = run;
        run += v;
    }
    rowptr[n] = e;
}

__global__ void scan_write(const int* __restrict__ counts, const int* __restrict__ bsums,
                           int* __restrict__ rowptr, int* __restrict__ cursor, int n) {
    __shared__ int sdata[256];
    int t = threadIdx.x;
    int base = blockIdx.x * 1024 + t * 4;
    int c[4];
    int s = 0;
#pragma unroll
    for (int i = 0; i < 4; ++i) {
        int idx = base + i;
        c[i] = (idx < n) ? counts[idx] : 0;
        s += c[i];
    }
    sdata[t] = s;
    __syncthreads();
    // inclusive Hillis-Steele scan over 256 per-thread sums
    for (int off = 1; off < 256; off <<= 1) {
        int val = (t >= off) ? sdata[t - off] : 0;
        __syncthreads();
        sdata[t] += val;
        __syncthreads();
    }
    int run = sdata[t] - s + bsums[blockIdx.x];   // exclusive prefix for this thread
#pragma unroll
    for (int i = 0; i < 4; ++i) {
        int idx = base + i;
        if (idx < n) {
            rowptr[idx] = run;
            cursor[idx] = run;
        }
        run += c[i];
    }
}

__global__ void fill_csr(const int* __restrict__ src, const int* __restrict__ dst,
                         int* __restrict__ cursor, int* __restrict__ col, int e) {
    int i = blockIdx.x * 256 + threadIdx.x;
    if (i >= e) return;
    int p = atomicAdd(&cursor[dst[i]], 1);
    col[p] = src[i];
}

// ---------------- GEMM: C[M,128] = A[M,128] @ W[128,128], fused epilogue ----------------
// mode 0: relu(A@W + bias)     (input projection)
// mode 1: dinv[row] * (A@W)    (conv layer, bias handled in aggregation)
// mode 2: A@W + bias           (output projection)

__global__ __launch_bounds__(256) void gemm128(
    const float* __restrict__ A, const float* __restrict__ W,
    const float* __restrict__ bias, const float* __restrict__ dinv,
    float* __restrict__ C, int M, int mode) {
    __shared__ __align__(16) float Wt[128 * 128];   // 64 KB, full weight
    __shared__ __align__(16) float At[32][68];      // transposed A chunk, padded
    __shared__ float dv[TM];

    int t = threadIdx.x;
    int r0 = blockIdx.x * TM;

    // stage full W (128x128): 16 float4 per thread, coalesced
    {
        const float4* Wg = (const float4*)W;
        float4* Ws = (float4*)Wt;
#pragma unroll
        for (int p = 0; p < 16; ++p) Ws[t + p * 256] = Wg[t + p * 256];
    }
    if (mode == 1 && t < TM) {
        int r = r0 + t;
        dv[t] = (r < M) ? dinv[r] : 0.0f;
    }

    float acc[8][4];
#pragma unroll
    for (int i = 0; i < 8; ++i)
#pragma unroll
        for (int j = 0; j < 4; ++j) acc[i][j] = 0.0f;

    int c4 = (t & 31) * 4;    // 32 col-groups * 4 cols = 128 cols
    int r8 = (t >> 5) * 8;    // 8 row-groups * 8 rows = 64 rows

    for (int k0 = 0; k0 < 128; k0 += 32) {
        __syncthreads();   // also covers W/dv staging on first iteration
        // stage A chunk transposed: 64 rows x 32 k -> At[k][r]
#pragma unroll
        for (int i = 0; i < 2; ++i) {
            int idx = t * 2 + i;          // 0..511 float4 slots
            int r = idx >> 3;             // 8 float4 per row
            int kk = (idx & 7) * 4;
            int gr = r0 + r;
            float4 vA = make_float4(0.f, 0.f, 0.f, 0.f);
            if (gr < M) vA = *(const float4*)(A + (size_t)gr * 128 + k0 + kk);
            At[kk + 0][r] = vA.x;
            At[kk + 1][r] = vA.y;
            At[kk + 2][r] = vA.z;
            At[kk + 3][r] = vA.w;
        }
        __syncthreads();
#pragma unroll
        for (int k = 0; k < 32; ++k) {
            float4 w4 = *(const float4*)&Wt[(k0 + k) * 128 + c4];
            float4 aL = *(const float4*)&At[k][r8];
            float4 aH = *(const float4*)&At[k][r8 + 4];
            float a[8] = {aL.x, aL.y, aL.z, aL.w, aH.x, aH.y, aH.z, aH.w};
            float w[4] = {w4.x, w4.y, w4.z, w4.w};
#pragma unroll
            for (int i = 0; i < 8; ++i)
#pragma unroll
                for (int j = 0; j < 4; ++j) acc[i][j] = fmaf(a[i], w[j], acc[i][j]);
        }
    }

    float b[4] = {0.f, 0.f, 0.f, 0.f};
    if (mode != 1) {
        float4 b4 = *(const float4*)(bias + c4);
        b[0] = b4.x; b[1] = b4.y; b[2] = b4.z; b[3] = b4.w;
    }
#pragma unroll
    for (int i = 0; i < 8; ++i) {
        int r = r0 + r8 + i;
        if (r >= M) continue;
        float o[4];
#pragma unroll
        for (int j = 0; j < 4; ++j) o[j] = acc[i][j];
        if (mode == 0) {
#pragma unroll
            for (int j = 0; j < 4; ++j) o[j] = fmaxf(o[j] + b[j], 0.0f);
        } else if (mode == 1) {
            float s = dv[r8 + i];
#pragma unroll
            for (int j = 0; j < 4; ++j) o[j] *= s;
        } else {
#pragma unroll
            for (int j = 0; j < 4; ++j) o[j] += b[j];
        }
        float4 o4 = make_float4(o[0], o[1], o[2], o[3]);
        *(float4*)(C + (size_t)r * 128 + c4) = o4;
    }
}

// ---------------- aggregation + bias + BN + ReLU ----------------
// one wave (64 lanes) per node; lane handles channels 2*lane, 2*lane+1

__global__ __launch_bounds__(256) void agg_bn_relu(
    const float* __restrict__ hw, const int* __restrict__ rowptr,
    const int* __restrict__ col, const float* __restrict__ dinv,
    const float* __restrict__ convb, const float* __restrict__ gamma,
    const float* __restrict__ beta, const float* __restrict__ mean,
    const float* __restrict__ var, float* __restrict__ hout, int n) {
    int lane = threadIdx.x & 63;
    int v = (blockIdx.x * 256 + threadIdx.x) >> 6;
    if (v >= n) return;

    const float2* base = (const float2*)hw;
    float2 acc = base[(size_t)v * 64 + lane];   // self-loop term hw'[v]

    int beg = rowptr[v], end = rowptr[v + 1];
    for (int p = beg; p < end; p += 64) {
        int cnt = end - p;
        if (cnt > 64) cnt = 64;
        int myc = (lane < cnt) ? col[p + lane] : 0;
        int j = 0;
        for (; j + 4 <= cnt; j += 4) {
            int u0 = __shfl(myc, j);
            int u1 = __shfl(myc, j + 1);
            int u2 = __shfl(myc, j + 2);
            int u3 = __shfl(myc, j + 3);
            float2 m0 = base[(size_t)u0 * 64 + lane];
            float2 m1 = base[(size_t)u1 * 64 + lane];
            float2 m2 = base[(size_t)u2 * 64 + lane];
            float2 m3 = base[(size_t)u3 * 64 + lane];
            acc.x += (m0.x + m1.x) + (m2.x + m3.x);
            acc.y += (m0.y + m1.y) + (m2.y + m3.y);
        }
        for (; j < cnt; ++j) {
            int u = __shfl(myc, j);
            float2 m = base[(size_t)u * 64 + lane];
            acc.x += m.x;
            acc.y += m.y;
        }
    }

    float dvv = dinv[v];
    int c0 = lane * 2;
    float2 g  = *(const float2*)(gamma + c0);
    float2 be = *(const float2*)(beta + c0);
    float2 mn = *(const float2*)(mean + c0);
    float2 va = *(const float2*)(var + c0);
    float2 cb = *(const float2*)(convb + c0);
    float s0 = g.x * rsqrtf(va.x + BN_EPS);
    float s1 = g.y * rsqrtf(va.y + BN_EPS);
    float o0 = (dvv * acc.x + cb.x - mn.x) * s0 + be.x;
    float o1 = (dvv * acc.y + cb.y - mn.y) * s1 + be.y;
    o0 = fmaxf(o0, 0.0f);
    o1 = fmaxf(o1, 0.0f);
    *(float2*)(hout + (size_t)v * 128 + c0) = make_float2(o0, o1);
}

// ---------------- launch ----------------

extern "C" void kernel_launch(void* const* d_in, const int* in_sizes, int n_in,
                              void* d_out, int out_size, void* d_ws, size_t ws_size,
                              hipStream_t stream) {
    const float* x      = (const float*)d_in[0];
    const void*  ei     = d_in[1];
    const float* lin0_w = (const float*)d_in[3];
    const float* lin0_b = (const float*)d_in[4];
    const float* lin1_w = (const float*)d_in[5];
    const float* lin1_b = (const float*)d_in[6];
    const float* conv_w = (const float*)d_in[7];
    const float* conv_b = (const float*)d_in[8];
    const float* bn_g   = (const float*)d_in[9];
    const float* bn_b   = (const float*)d_in[10];
    const float* bn_m   = (const float*)d_in[11];
    const float* bn_v   = (const float*)d_in[12];

    int n = in_sizes[0] / HIDC;   // 100000
    int e = in_sizes[1] / 2;      // 1600000

    char* ws = (char*)d_ws;
    size_t off = 0;
    auto alloc = [&](size_t bytes) -> void* {
        void* p = ws + off;
        off += (bytes + 255) & ~(size_t)255;
        return p;
    };
    float* h      = (float*)alloc((size_t)n * HIDC * 4);
    float* hw     = (float*)alloc((size_t)n * HIDC * 4);
    int*   src    = (int*)alloc((size_t)e * 4);
    int*   dst    = (int*)alloc((size_t)e * 4);
    int*   col    = (int*)alloc((size_t)e * 4);
    int*   counts = (int*)alloc((size_t)n * 4);
    float* dinv   = (float*)alloc((size_t)n * 4);
    int*   rowptr = (int*)alloc(((size_t)n + 1) * 4);
    int*   cursor = (int*)alloc((size_t)n * 4);
    int*   bsums  = (int*)alloc(4096);
    int*   flag   = (int*)alloc(256);

    hipMemsetAsync(counts, 0, (size_t)n * 4, stream);

    detect64<<<1, 64, 0, stream>>>((const unsigned int*)ei, flag);

    int eb = (e + 255) / 256;
    convert_count<<<eb, 256, 0, stream>>>(ei, flag, src, dst, counts, e);

    int nb256 = (n + 255) / 256;
    compute_dinv<<<nb256, 256, 0, stream>>>(counts, dinv, n);

    int nbs = (n + 1023) / 1024;
    scan_block_totals<<<nbs, 256, 0, stream>>>(counts, bsums, n);
    scan_bsums<<<1, 64, 0, stream>>>(bsums, nbs, rowptr, n, e);
    scan_write<<<nbs, 256, 0, stream>>>(counts, bsums, rowptr, cursor, n);
    fill_csr<<<eb, 256, 0, stream>>>(src, dst, cursor, col, e);

    int gb = (n + TM - 1) / TM;
    // input projection: h = relu(x @ W0 + b0)
    gemm128<<<gb, 256, 0, stream>>>(x, lin0_w, lin0_b, nullptr, h, n, 0);

    for (int l = 0; l < 3; ++l) {
        // hw = dinv * (h @ Wl)
        gemm128<<<gb, 256, 0, stream>>>(h, conv_w + (size_t)l * HIDC * HIDC, nullptr, dinv, hw, n, 1);
        // h = relu(BN(dinv*(hw[v] + sum hw[col]) + conv_b))
        int ab = (n + 3) / 4;
        agg_bn_relu<<<ab, 256, 0, stream>>>(hw, rowptr, col, dinv,
                                            conv_b + (size_t)l * HIDC,
                                            bn_g + (size_t)l * HIDC, bn_b + (size_t)l * HIDC,
                                            bn_m + (size_t)l * HIDC, bn_v + (size_t)l * HIDC,
                                            h, n);
    }
    // output projection: out = h @ W4 + b4
    gemm128<<<gb, 256, 0, stream>>>(h, lin1_w, lin1_b, nullptr, (float*)d_out, n, 2);
}

// Round 2
// 605.763 us; speedup vs baseline: 1.3930x; 1.3930x over previous
//
#include <hip/hip_runtime.h>
#include <hip/hip_fp16.h>

// LinkPredictorBackbone: GCN backbone, N=100000 nodes, E=1600000 edges, C=128.
// Pipeline per launch:
//   1. detect edge_index dtype (int64 vs int32); convert to int2 pairs + in-degree counts
//   2. dinv[v] = rsqrt(count+1); exclusive scan of counts -> CSR rowptr
//   3. bin pairs into bucket-major (bucket = dst>>8) order via LDS staging
//      (bucket base == rowptr[b*256], derived free from the node scan)
//   4. one workgroup per bucket scatters col[] within its private 8KB window
//   5. h = relu(x @ W0 + b0)
//   6. 3x { hw(fp16) = dinv * (h @ Wl) ; h = relu(BN(dinv*(hw[v]+sum hw[col]) + conv_b)) }
//   7. out = h @ W4 + b4

#define HIDC 128
#define BN_EPS 1e-5f
#define TM 64
#define DPB 256          // dsts per bucket
#define NBK 512          // bucket array size (>= ceil(N/DPB))
#define BIN_CHUNK 8192   // edges per binning block

// ---------------- graph build kernels ----------------

__global__ void detect64(const unsigned int* ei, int* flag) {
    if (threadIdx.x != 0 || blockIdx.x != 0) return;
    int is64 = 1;
    for (int i = 0; i < 64; ++i) {
        if (ei[2 * i + 1] != 0u) { is64 = 0; break; }
    }
    *flag = is64;
}

__global__ void convert_pairs(const void* __restrict__ ei, const int* __restrict__ flag,
                              int2* __restrict__ pairs, int* __restrict__ counts, int e) {
    int i = blockIdx.x * 256 + threadIdx.x;
    if (i >= e) return;
    int s, d;
    if (*flag) {
        const long long* p = (const long long*)ei;
        s = (int)p[i];
        d = (int)p[e + i];
    } else {
        const int* p = (const int*)ei;
        s = p[i];
        d = p[e + i];
    }
    pairs[i] = make_int2(s, d);
    atomicAdd(&counts[d], 1);
}

__global__ void compute_dinv(const int* __restrict__ counts, float* __restrict__ dinv, int n) {
    int i = blockIdx.x * 256 + threadIdx.x;
    if (i >= n) return;
    dinv[i] = rsqrtf((float)(counts[i] + 1));   // +1: self loop
}

// scan: CHUNK=1024 per block (256 threads x 4)
__global__ void scan_block_totals(const int* __restrict__ counts, int* __restrict__ bsums, int n) {
    __shared__ int sdata[256];
    int t = threadIdx.x;
    int base = blockIdx.x * 1024 + t * 4;
    int s = 0;
#pragma unroll
    for (int i = 0; i < 4; ++i) {
        int idx = base + i;
        if (idx < n) s += counts[idx];
    }
    sdata[t] = s;
    __syncthreads();
    for (int off = 128; off > 0; off >>= 1) {
        if (t < off) sdata[t] += sdata[t + off];
        __syncthreads();
    }
    if (t == 0) bsums[blockIdx.x] = sdata[0];
}

__global__ void scan_bsums(int* bsums, int nb, int* rowptr, int n, int e) {
    if (threadIdx.x != 0 || blockIdx.x != 0) return;
    int run = 0;
    for (int i = 0; i < nb; ++i) {
        int v = bsums[i];
        bsums[i] = run;
        run += v;
    }
    rowptr[n] = e;
}

__global__ void scan_write(const int* __restrict__ counts, const int* __restrict__ bsums,
                           int* __restrict__ rowptr, int n) {
    __shared__ int sdata[256];
    int t = threadIdx.x;
    int base = blockIdx.x * 1024 + t * 4;
    int c[4];
    int s = 0;
#pragma unroll
    for (int i = 0; i < 4; ++i) {
        int idx = base + i;
        c[i] = (idx < n) ? counts[idx] : 0;
        s += c[i];
    }
    sdata[t] = s;
    __syncthreads();
    for (int off = 1; off < 256; off <<= 1) {
        int val = (t >= off) ? sdata[t - off] : 0;
        __syncthreads();
        sdata[t] += val;
        __syncthreads();
    }
    int run = sdata[t] - s + bsums[blockIdx.x];   // exclusive prefix
#pragma unroll
    for (int i = 0; i < 4; ++i) {
        int idx = base + i;
        if (idx < n) rowptr[idx] = run;
        run += c[i];
    }
}

// bc[b] = rowptr[b*DPB]  (bucket write cursors for the binning phase)
__global__ void init_bc(const int* __restrict__ rowptr, int* __restrict__ bc, int n, int nbk) {
    int b = threadIdx.x + blockIdx.x * 512;
    if (b >= nbk) return;
    int d = b * DPB;
    if (d > n) d = n;
    bc[b] = rowptr[d];
}

// bin pairs into bucket-major order with coalesced flushes via LDS staging
__global__ __launch_bounds__(256) void bin_pairs(const int2* __restrict__ pairs,
                                                 int* __restrict__ bc,
                                                 int2* __restrict__ staged, int e) {
    __shared__ int hist[NBK];      // later reused as local placement cursor
    __shared__ int lstart[NBK];
    __shared__ int gbase[NBK];
    __shared__ int sdata[256];
    __shared__ int2 stage[BIN_CHUNK];   // 64 KB

    int t = threadIdx.x;
    int base = blockIdx.x * BIN_CHUNK;
    int cnt = e - base;
    if (cnt > BIN_CHUNK) cnt = BIN_CHUNK;

    for (int i = t; i < NBK; i += 256) hist[i] = 0;
    __syncthreads();
    for (int i = t; i < cnt; i += 256) {
        int d = pairs[base + i].y;
        atomicAdd(&hist[d >> 8], 1);
    }
    __syncthreads();

    // exclusive scan of hist[0..NBK) ; each thread owns slots 2t, 2t+1
    int a0 = hist[2 * t], a1 = hist[2 * t + 1];
    int s = a0 + a1;
    sdata[t] = s;
    __syncthreads();
    for (int off = 1; off < 256; off <<= 1) {
        int val = (t >= off) ? sdata[t - off] : 0;
        __syncthreads();
        sdata[t] += val;
        __syncthreads();
    }
    int excl = sdata[t] - s;
    lstart[2 * t] = excl;
    lstart[2 * t + 1] = excl + a0;
    // reserve global bucket space; reuse hist as local cursor
    if (a0 > 0) gbase[2 * t] = atomicAdd(&bc[2 * t], a0);
    if (a1 > 0) gbase[2 * t + 1] = atomicAdd(&bc[2 * t + 1], a1);
    hist[2 * t] = excl;
    hist[2 * t + 1] = excl + a0;
    __syncthreads();

    // place into LDS staging, bucket-sorted
    for (int i = t; i < cnt; i += 256) {
        int2 p = pairs[base + i];
        int pos = atomicAdd(&hist[p.y >> 8], 1);
        stage[pos] = p;
    }
    __syncthreads();

    // flush: consecutive LDS slots within a bucket -> consecutive global slots
    for (int i = t; i < cnt; i += 256) {
        int2 p = stage[i];
        int b = p.y >> 8;
        staged[gbase[b] + (i - lstart[b])] = p;
    }
}

// one workgroup per bucket: scatter col[] within a private ~8KB window
__global__ __launch_bounds__(256) void fill_bucket(const int2* __restrict__ staged,
                                                   const int* __restrict__ rowptr,
                                                   int* __restrict__ col, int n) {
    __shared__ int cur[DPB];
    int b = blockIdx.x;
    int dstart = b * DPB;
    int dcnt = n - dstart;
    if (dcnt > DPB) dcnt = DPB;
    int t = threadIdx.x;
    if (t < dcnt) cur[t] = rowptr[dstart + t];
    int estart = rowptr[dstart];
    int dend = dstart + DPB;
    if (dend > n) dend = n;
    int eend = rowptr[dend];
    __syncthreads();
    for (int i = estart + t; i < eend; i += 256) {
        int2 p = staged[i];
        int pos = atomicAdd(&cur[p.y - dstart], 1);
        col[pos] = p.x;
    }
}

// ---------------- GEMM: C[M,128] = A[M,128] @ W[128,128], fused epilogue ----------------
// mode 0: relu(A@W + bias) -> float      (input projection)
// mode 1: dinv[row] * (A@W) -> fp16      (conv layer message buffer)
// mode 2: A@W + bias -> float            (output projection)

__global__ __launch_bounds__(256) void gemm128(
    const float* __restrict__ A, const float* __restrict__ W,
    const float* __restrict__ bias, const float* __restrict__ dinv,
    void* __restrict__ Cout, int M, int mode) {
    __shared__ __align__(16) float Wt[128 * 128];   // 64 KB, full weight
    __shared__ __align__(16) float At[32][68];      // transposed A chunk, padded
    __shared__ float dv[TM];

    int t = threadIdx.x;
    int r0 = blockIdx.x * TM;

    {
        const float4* Wg = (const float4*)W;
        float4* Ws = (float4*)Wt;
#pragma unroll
        for (int p = 0; p < 16; ++p) Ws[t + p * 256] = Wg[t + p * 256];
    }
    if (mode == 1 && t < TM) {
        int r = r0 + t;
        dv[t] = (r < M) ? dinv[r] : 0.0f;
    }

    float acc[8][4];
#pragma unroll
    for (int i = 0; i < 8; ++i)
#pragma unroll
        for (int j = 0; j < 4; ++j) acc[i][j] = 0.0f;

    int c4 = (t & 31) * 4;
    int r8 = (t >> 5) * 8;

    for (int k0 = 0; k0 < 128; k0 += 32) {
        __syncthreads();
#pragma unroll
        for (int i = 0; i < 2; ++i) {
            int idx = t * 2 + i;
            int r = idx >> 3;
            int kk = (idx & 7) * 4;
            int gr = r0 + r;
            float4 vA = make_float4(0.f, 0.f, 0.f, 0.f);
            if (gr < M) vA = *(const float4*)(A + (size_t)gr * 128 + k0 + kk);
            At[kk + 0][r] = vA.x;
            At[kk + 1][r] = vA.y;
            At[kk + 2][r] = vA.z;
            At[kk + 3][r] = vA.w;
        }
        __syncthreads();
#pragma unroll
        for (int k = 0; k < 32; ++k) {
            float4 w4 = *(const float4*)&Wt[(k0 + k) * 128 + c4];
            float4 aL = *(const float4*)&At[k][r8];
            float4 aH = *(const float4*)&At[k][r8 + 4];
            float a[8] = {aL.x, aL.y, aL.z, aL.w, aH.x, aH.y, aH.z, aH.w};
            float w[4] = {w4.x, w4.y, w4.z, w4.w};
#pragma unroll
            for (int i = 0; i < 8; ++i)
#pragma unroll
                for (int j = 0; j < 4; ++j) acc[i][j] = fmaf(a[i], w[j], acc[i][j]);
        }
    }

    float b[4] = {0.f, 0.f, 0.f, 0.f};
    if (mode != 1) {
        float4 b4 = *(const float4*)(bias + c4);
        b[0] = b4.x; b[1] = b4.y; b[2] = b4.z; b[3] = b4.w;
    }
#pragma unroll
    for (int i = 0; i < 8; ++i) {
        int r = r0 + r8 + i;
        if (r >= M) continue;
        float o[4];
#pragma unroll
        for (int j = 0; j < 4; ++j) o[j] = acc[i][j];
        if (mode == 0) {
#pragma unroll
            for (int j = 0; j < 4; ++j) o[j] = fmaxf(o[j] + b[j], 0.0f);
            *(float4*)((float*)Cout + (size_t)r * 128 + c4) =
                make_float4(o[0], o[1], o[2], o[3]);
        } else if (mode == 1) {
            float s = dv[r8 + i];
            __half2 ha = __floats2half2_rn(s * o[0], s * o[1]);
            __half2 hb = __floats2half2_rn(s * o[2], s * o[3]);
            uint2 pk;
            pk.x = *(unsigned int*)&ha;
            pk.y = *(unsigned int*)&hb;
            *(uint2*)((__half*)Cout + (size_t)r * 128 + c4) = pk;
        } else {
#pragma unroll
            for (int j = 0; j < 4; ++j) o[j] += b[j];
            *(float4*)((float*)Cout + (size_t)r * 128 + c4) =
                make_float4(o[0], o[1], o[2], o[3]);
        }
    }
}

// ---------------- aggregation + bias + BN + ReLU ----------------
// one wave (64 lanes) per node; lane handles channels 2*lane, 2*lane+1 (half2 gather)

__global__ __launch_bounds__(256) void agg_bn_relu(
    const __half2* __restrict__ hw, const int* __restrict__ rowptr,
    const int* __restrict__ col, const float* __restrict__ dinv,
    const float* __restrict__ convb, const float* __restrict__ gamma,
    const float* __restrict__ beta, const float* __restrict__ mean,
    const float* __restrict__ var, float* __restrict__ hout, int n) {
    int lane = threadIdx.x & 63;
    int v = (blockIdx.x * 256 + threadIdx.x) >> 6;
    if (v >= n) return;

    float2 acc = __half22float2(hw[(size_t)v * 64 + lane]);   // self-loop term

    int beg = rowptr[v], end = rowptr[v + 1];
    for (int p = beg; p < end; p += 64) {
        int cnt = end - p;
        if (cnt > 64) cnt = 64;
        int myc = (lane < cnt) ? col[p + lane] : 0;
        int j = 0;
        for (; j + 4 <= cnt; j += 4) {
            int u0 = __shfl(myc, j);
            int u1 = __shfl(myc, j + 1);
            int u2 = __shfl(myc, j + 2);
            int u3 = __shfl(myc, j + 3);
            float2 m0 = __half22float2(hw[(size_t)u0 * 64 + lane]);
            float2 m1 = __half22float2(hw[(size_t)u1 * 64 + lane]);
            float2 m2 = __half22float2(hw[(size_t)u2 * 64 + lane]);
            float2 m3 = __half22float2(hw[(size_t)u3 * 64 + lane]);
            acc.x += (m0.x + m1.x) + (m2.x + m3.x);
            acc.y += (m0.y + m1.y) + (m2.y + m3.y);
        }
        for (; j < cnt; ++j) {
            int u = __shfl(myc, j);
            float2 m = __half22float2(hw[(size_t)u * 64 + lane]);
            acc.x += m.x;
            acc.y += m.y;
        }
    }

    float dvv = dinv[v];
    int c0 = lane * 2;
    float2 g  = *(const float2*)(gamma + c0);
    float2 be = *(const float2*)(beta + c0);
    float2 mn = *(const float2*)(mean + c0);
    float2 va = *(const float2*)(var + c0);
    float2 cb = *(const float2*)(convb + c0);
    float s0 = g.x * rsqrtf(va.x + BN_EPS);
    float s1 = g.y * rsqrtf(va.y + BN_EPS);
    float o0 = (dvv * acc.x + cb.x - mn.x) * s0 + be.x;
    float o1 = (dvv * acc.y + cb.y - mn.y) * s1 + be.y;
    o0 = fmaxf(o0, 0.0f);
    o1 = fmaxf(o1, 0.0f);
    *(float2*)(hout + (size_t)v * 128 + c0) = make_float2(o0, o1);
}

// ---------------- launch ----------------

extern "C" void kernel_launch(void* const* d_in, const int* in_sizes, int n_in,
                              void* d_out, int out_size, void* d_ws, size_t ws_size,
                              hipStream_t stream) {
    const float* x      = (const float*)d_in[0];
    const void*  ei     = d_in[1];
    const float* lin0_w = (const float*)d_in[3];
    const float* lin0_b = (const float*)d_in[4];
    const float* lin1_w = (const float*)d_in[5];
    const float* lin1_b = (const float*)d_in[6];
    const float* conv_w = (const float*)d_in[7];
    const float* conv_b = (const float*)d_in[8];
    const float* bn_g   = (const float*)d_in[9];
    const float* bn_b   = (const float*)d_in[10];
    const float* bn_m   = (const float*)d_in[11];
    const float* bn_v   = (const float*)d_in[12];

    int n = in_sizes[0] / HIDC;   // 100000
    int e = in_sizes[1] / 2;      // 1600000
    int nbk = (n + DPB - 1) / DPB;   // 391

    char* ws = (char*)d_ws;
    size_t off = 0;
    auto alloc = [&](size_t bytes) -> void* {
        void* p = ws + off;
        off += (bytes + 255) & ~(size_t)255;
        return p;
    };
    float*   h      = (float*)alloc((size_t)n * HIDC * 4);
    __half2* hw     = (__half2*)alloc((size_t)n * HIDC * 2);
    int2*    pairs  = (int2*)alloc((size_t)e * 8);
    int2*    staged = (int2*)alloc((size_t)e * 8);
    int*     col    = (int*)alloc((size_t)e * 4);
    int*     counts = (int*)alloc((size_t)n * 4);
    float*   dinv   = (float*)alloc((size_t)n * 4);
    int*     rowptr = (int*)alloc(((size_t)n + 1) * 4);
    int*     bc     = (int*)alloc((size_t)NBK * 4);
    int*     bsums  = (int*)alloc(4096);
    int*     flag   = (int*)alloc(256);

    hipMemsetAsync(counts, 0, (size_t)n * 4, stream);

    detect64<<<1, 64, 0, stream>>>((const unsigned int*)ei, flag);

    int eb = (e + 255) / 256;
    convert_pairs<<<eb, 256, 0, stream>>>(ei, flag, pairs, counts, e);

    int nb256 = (n + 255) / 256;
    compute_dinv<<<nb256, 256, 0, stream>>>(counts, dinv, n);

    int nbs = (n + 1023) / 1024;
    scan_block_totals<<<nbs, 256, 0, stream>>>(counts, bsums, n);
    scan_bsums<<<1, 64, 0, stream>>>(bsums, nbs, rowptr, n, e);
    scan_write<<<nbs, 256, 0, stream>>>(counts, bsums, rowptr, n);

    init_bc<<<1, 512, 0, stream>>>(rowptr, bc, n, nbk);
    int binb = (e + BIN_CHUNK - 1) / BIN_CHUNK;
    bin_pairs<<<binb, 256, 0, stream>>>(pairs, bc, staged, e);
    fill_bucket<<<nbk, 256, 0, stream>>>(staged, rowptr, col, n);

    int gb = (n + TM - 1) / TM;
    gemm128<<<gb, 256, 0, stream>>>(x, lin0_w, lin0_b, nullptr, h, n, 0);

    for (int l = 0; l < 3; ++l) {
        gemm128<<<gb, 256, 0, stream>>>(h, conv_w + (size_t)l * HIDC * HIDC, nullptr, dinv, hw, n, 1);
        int ab = (n + 3) / 4;
        agg_bn_relu<<<ab, 256, 0, stream>>>(hw, rowptr, col, dinv,
                                            conv_b + (size_t)l * HIDC,
                                            bn_g + (size_t)l * HIDC, bn_b + (size_t)l * HIDC,
                                            bn_m + (size_t)l * HIDC, bn_v + (size_t)l * HIDC,
                                            h, n);
    }
    gemm128<<<gb, 256, 0, stream>>>(h, lin1_w, lin1_b, nullptr, d_out, n, 2);
}

// Round 3
// 389.966 us; speedup vs baseline: 2.1639x; 1.5534x over previous
//
#include <hip/hip_runtime.h>
#include <hip/hip_fp16.h>

// LinkPredictorBackbone: GCN backbone, N=100000 nodes, E=1600000 edges, C=128.
// Round 3 pipeline:
//   graph build: bucket-count (LDS hist) -> bucket scan -> bin (bucket-major)
//                -> fill_bucket (per-node count/rowptr/dinv/col all in-LDS)
//   weights: pack all 5 128x128 fp32 W into bf16 hi/lo MFMA B-fragment records
//   gemm_mfma: split-bf16 (hi*hi + hi*lo + lo*hi) 16x16x32 MFMA, A from global,
//              Wf from 64KB LDS, fused epilogue (relu+bias / dinv*->fp16 / bias)
//   agg_bn_relu: wave-per-node fp16 gather + BN + ReLU (unchanged)

#define HIDC 128
#define BN_EPS 1e-5f
#define DPB 256          // dsts per bucket
#define NBK 512          // bucket array size (>= ceil(N/DPB))
#define BIN_CHUNK 8192   // edges per binning block

typedef short bf16x8 __attribute__((ext_vector_type(8)));
typedef float f32x4 __attribute__((ext_vector_type(4)));

__device__ __forceinline__ unsigned short f2bf_rn(float x) {
    unsigned int u = __float_as_uint(x);
    unsigned int r = u + 0x7fffu + ((u >> 16) & 1u);
    return (unsigned short)(r >> 16);
}
__device__ __forceinline__ float bf2f(unsigned short b) {
    return __uint_as_float(((unsigned int)b) << 16);
}

// ---------------- graph build ----------------

__global__ void detect64(const unsigned int* ei, int* flag) {
    if (threadIdx.x != 0 || blockIdx.x != 0) return;
    int is64 = 1;
    for (int i = 0; i < 64; ++i) {
        if (ei[2 * i + 1] != 0u) { is64 = 0; break; }
    }
    *flag = is64;
}

__global__ __launch_bounds__(256) void bucket_count(const void* __restrict__ ei,
                                                    const int* __restrict__ flag,
                                                    int* __restrict__ bkt, int e) {
    __shared__ int h[NBK];
    int t = threadIdx.x;
    for (int i = t; i < NBK; i += 256) h[i] = 0;
    __syncthreads();
    int base = blockIdx.x * BIN_CHUNK;
    int cnt = e - base;
    if (cnt > BIN_CHUNK) cnt = BIN_CHUNK;
    if (*flag) {
        const long long* pd = (const long long*)ei + e;
        for (int i = t; i < cnt; i += 256) atomicAdd(&h[((int)pd[base + i]) >> 8], 1);
    } else {
        const int* pd = (const int*)ei + e;
        for (int i = t; i < cnt; i += 256) atomicAdd(&h[pd[base + i] >> 8], 1);
    }
    __syncthreads();
    for (int i = t; i < NBK; i += 256) if (h[i]) atomicAdd(&bkt[i], h[i]);
}

// single block of 512: exclusive scan of bucket counts -> bbase (cursor copy bc)
__global__ void scan_buckets(const int* __restrict__ bkt, int* __restrict__ bbase,
                             int* __restrict__ bc, int* __restrict__ rowptr,
                             int n, int e, int nbk) {
    __shared__ int s[NBK];
    int t = threadIdx.x;
    int v = (t < nbk) ? bkt[t] : 0;
    s[t] = v;
    __syncthreads();
    for (int off = 1; off < NBK; off <<= 1) {
        int val = (t >= off) ? s[t - off] : 0;
        __syncthreads();
        s[t] += val;
        __syncthreads();
    }
    int excl = s[t] - v;     // exclusive prefix (== e for t >= nbk)
    bbase[t] = excl;
    bc[t] = excl;
    if (t == 0) rowptr[n] = e;
}

// bin edges into bucket-major order with coalesced flushes via LDS staging
__global__ __launch_bounds__(256) void bin_pairs(const void* __restrict__ ei,
                                                 const int* __restrict__ flag,
                                                 int* __restrict__ bc,
                                                 int2* __restrict__ staged, int e) {
    __shared__ int hist[NBK];      // later reused as local placement cursor
    __shared__ int lstart[NBK];
    __shared__ int gbase[NBK];
    __shared__ int sdata[256];
    __shared__ int2 stage[BIN_CHUNK];   // 64 KB

    int t = threadIdx.x;
    int base = blockIdx.x * BIN_CHUNK;
    int cnt = e - base;
    if (cnt > BIN_CHUNK) cnt = BIN_CHUNK;
    int is64 = *flag;

    for (int i = t; i < NBK; i += 256) hist[i] = 0;
    __syncthreads();
    if (is64) {
        const long long* pd = (const long long*)ei + e;
        for (int i = t; i < cnt; i += 256) atomicAdd(&hist[((int)pd[base + i]) >> 8], 1);
    } else {
        const int* pd = (const int*)ei + e;
        for (int i = t; i < cnt; i += 256) atomicAdd(&hist[pd[base + i] >> 8], 1);
    }
    __syncthreads();

    // exclusive scan of hist[0..NBK); thread owns slots 2t, 2t+1
    int a0 = hist[2 * t], a1 = hist[2 * t + 1];
    int s = a0 + a1;
    sdata[t] = s;
    __syncthreads();
    for (int off = 1; off < 256; off <<= 1) {
        int val = (t >= off) ? sdata[t - off] : 0;
        __syncthreads();
        sdata[t] += val;
        __syncthreads();
    }
    int excl = sdata[t] - s;
    lstart[2 * t] = excl;
    lstart[2 * t + 1] = excl + a0;
    if (a0 > 0) gbase[2 * t] = atomicAdd(&bc[2 * t], a0);
    if (a1 > 0) gbase[2 * t + 1] = atomicAdd(&bc[2 * t + 1], a1);
    hist[2 * t] = excl;
    hist[2 * t + 1] = excl + a0;
    __syncthreads();

    // place into LDS staging, bucket-sorted
    if (is64) {
        const long long* ps = (const long long*)ei;
        const long long* pd = ps + e;
        for (int i = t; i < cnt; i += 256) {
            int2 p = make_int2((int)ps[base + i], (int)pd[base + i]);
            int pos = atomicAdd(&hist[p.y >> 8], 1);
            stage[pos] = p;
        }
    } else {
        const int* ps = (const int*)ei;
        const int* pd = ps + e;
        for (int i = t; i < cnt; i += 256) {
            int2 p = make_int2(ps[base + i], pd[base + i]);
            int pos = atomicAdd(&hist[p.y >> 8], 1);
            stage[pos] = p;
        }
    }
    __syncthreads();

    // flush: consecutive LDS slots within a bucket -> consecutive global slots
    for (int i = t; i < cnt; i += 256) {
        int2 p = stage[i];
        int b = p.y >> 8;
        staged[gbase[b] + (i - lstart[b])] = p;
    }
}

// one workgroup per bucket: per-node counts/rowptr/dinv + col scatter, all local
__global__ __launch_bounds__(256) void fill_bucket(const int2* __restrict__ staged,
                                                   const int* __restrict__ bbase,
                                                   float* __restrict__ dinv,
                                                   int* __restrict__ rowptr,
                                                   int* __restrict__ col, int n) {
    __shared__ int cnt[DPB];
    __shared__ int scn[DPB];
    int b = blockIdx.x;
    int t = threadIdx.x;
    int dstart = b * DPB;
    int ebeg = bbase[b], eend = bbase[b + 1];
    cnt[t] = 0;
    __syncthreads();
    for (int i = ebeg + t; i < eend; i += 256)
        atomicAdd(&cnt[staged[i].y - dstart], 1);
    __syncthreads();
    int my = cnt[t];
    scn[t] = my;
    __syncthreads();
    for (int off = 1; off < 256; off <<= 1) {
        int val = (t >= off) ? scn[t - off] : 0;
        __syncthreads();
        scn[t] += val;
        __syncthreads();
    }
    int excl = scn[t] - my;
    int v = dstart + t;
    if (v < n) {
        rowptr[v] = ebeg + excl;
        dinv[v] = rsqrtf((float)(my + 1));   // +1: self loop
    }
    cnt[t] = excl;   // reuse as local cursor
    __syncthreads();
    for (int i = ebeg + t; i < eend; i += 256) {
        int2 p = staged[i];
        int pos = atomicAdd(&cnt[p.y - dstart], 1);
        col[ebeg + pos] = p.x;
    }
}

// ---------------- weight packing: fp32 W[128][128] -> bf16 hi/lo B-fragments ----------------
// record layout per matrix: wf[mat*4096 + part*2048 + (ks*8 + t)*64 + lane] (uint4 = 8 bf16)
// fragment element j of lane l = W[ks*32 + (l>>4)*8 + j][t*16 + (l&15)]

__global__ __launch_bounds__(256) void pack_w(const float* __restrict__ lin0,
                                              const float* __restrict__ conv,
                                              const float* __restrict__ lin1,
                                              uint4* __restrict__ wf) {
    int tid = blockIdx.x * 256 + threadIdx.x;
    if (tid >= 5 * 2048) return;
    int mat = tid >> 11;
    int rem = tid & 2047;
    int ks = rem >> 9;
    int tt = (rem >> 6) & 7;
    int l = rem & 63;
    const float* W = (mat == 0) ? lin0 : (mat == 4) ? lin1 : conv + (size_t)(mat - 1) * 16384;
    int kbase = ks * 32 + (l >> 4) * 8;
    int c = tt * 16 + (l & 15);
    unsigned int hi[4], lo[4];
#pragma unroll
    for (int d = 0; d < 4; ++d) {
        float w0 = W[(kbase + 2 * d) * 128 + c];
        float w1 = W[(kbase + 2 * d + 1) * 128 + c];
        unsigned short h0 = f2bf_rn(w0), h1 = f2bf_rn(w1);
        unsigned short l0 = f2bf_rn(w0 - bf2f(h0)), l1 = f2bf_rn(w1 - bf2f(h1));
        hi[d] = (unsigned int)h0 | ((unsigned int)h1 << 16);
        lo[d] = (unsigned int)l0 | ((unsigned int)l1 << 16);
    }
    int rec = (ks * 8 + tt) * 64 + l;
    wf[(size_t)mat * 4096 + rec] = make_uint4(hi[0], hi[1], hi[2], hi[3]);
    wf[(size_t)mat * 4096 + 2048 + rec] = make_uint4(lo[0], lo[1], lo[2], lo[3]);
}

// ---------------- MFMA GEMM: C[M,128] = A[M,128] @ W[128,128] ----------------
// 512 threads = 8 waves, M-tile 128 (16 rows/wave). Split bf16: hi*hi + hi*lo + lo*hi.
// mode 0: relu(A@W + bias) -> float   mode 1: dinv[row]*(A@W) -> fp16   mode 2: A@W + bias -> float

__global__ __launch_bounds__(512) void gemm_mfma(
    const float* __restrict__ A, const uint4* __restrict__ wf,
    const float* __restrict__ bias, const float* __restrict__ dinv,
    void* __restrict__ Cout, int M, int mode) {
    __shared__ uint4 WfL[4096];   // 64 KB: [part*2048 + rec]

    int t = threadIdx.x;
#pragma unroll
    for (int i = 0; i < 8; ++i) WfL[t + i * 512] = wf[t + i * 512];

    int wave = t >> 6, lane = t & 63;
    int lrow = lane & 15, lgrp = lane >> 4;
    int r0 = blockIdx.x * 128 + wave * 16;

    f32x4 acc[8];
#pragma unroll
    for (int i = 0; i < 8; ++i) acc[i] = (f32x4){0.f, 0.f, 0.f, 0.f};

    __syncthreads();

    int arow = r0 + lrow;
    if (arow >= M) arow = M - 1;          // clamp (stores are guarded)
    const float* ap = A + (size_t)arow * 128 + lgrp * 8;

#pragma unroll
    for (int ks = 0; ks < 4; ++ks) {
        float4 v0 = *(const float4*)(ap + ks * 32);
        float4 v1 = *(const float4*)(ap + ks * 32 + 4);
        float av[8] = {v0.x, v0.y, v0.z, v0.w, v1.x, v1.y, v1.z, v1.w};
        bf16x8 ahi, alo;
#pragma unroll
        for (int j = 0; j < 8; ++j) {
            unsigned short h = f2bf_rn(av[j]);
            ahi[j] = (short)h;
            alo[j] = (short)f2bf_rn(av[j] - bf2f(h));
        }
#pragma unroll
        for (int tt = 0; tt < 8; ++tt) {
            bf16x8 bhi = *(const bf16x8*)&WfL[(ks * 8 + tt) * 64 + lane];
            bf16x8 blo = *(const bf16x8*)&WfL[2048 + (ks * 8 + tt) * 64 + lane];
            acc[tt] = __builtin_amdgcn_mfma_f32_16x16x32_bf16(ahi, bhi, acc[tt], 0, 0, 0);
            acc[tt] = __builtin_amdgcn_mfma_f32_16x16x32_bf16(ahi, blo, acc[tt], 0, 0, 0);
            acc[tt] = __builtin_amdgcn_mfma_f32_16x16x32_bf16(alo, bhi, acc[tt], 0, 0, 0);
        }
    }

    // epilogue: D row = r0 + lgrp*4 + j, col = tt*16 + lrow
    int rbase = r0 + lgrp * 4;
    float dv[4] = {0.f, 0.f, 0.f, 0.f};
    if (mode == 1) {
#pragma unroll
        for (int j = 0; j < 4; ++j) dv[j] = (rbase + j < M) ? dinv[rbase + j] : 0.f;
    }
#pragma unroll
    for (int tt = 0; tt < 8; ++tt) {
        int c = tt * 16 + lrow;
        float bc_ = (mode != 1) ? bias[c] : 0.f;
#pragma unroll
        for (int j = 0; j < 4; ++j) {
            int r = rbase + j;
            if (r >= M) continue;
            float val = acc[tt][j];
            if (mode == 0) {
                ((float*)Cout)[(size_t)r * 128 + c] = fmaxf(val + bc_, 0.f);
            } else if (mode == 1) {
                ((__half*)Cout)[(size_t)r * 128 + c] = __float2half(val * dv[j]);
            } else {
                ((float*)Cout)[(size_t)r * 128 + c] = val + bc_;
            }
        }
    }
}

// ---------------- aggregation + bias + BN + ReLU ----------------
// one wave (64 lanes) per node; lane handles channels 2*lane, 2*lane+1 (half2 gather)

__global__ __launch_bounds__(256) void agg_bn_relu(
    const __half2* __restrict__ hw, const int* __restrict__ rowptr,
    const int* __restrict__ col, const float* __restrict__ dinv,
    const float* __restrict__ convb, const float* __restrict__ gamma,
    const float* __restrict__ beta, const float* __restrict__ mean,
    const float* __restrict__ var, float* __restrict__ hout, int n) {
    int lane = threadIdx.x & 63;
    int v = (blockIdx.x * 256 + threadIdx.x) >> 6;
    if (v >= n) return;

    float2 acc = __half22float2(hw[(size_t)v * 64 + lane]);   // self-loop term

    int beg = rowptr[v], end = rowptr[v + 1];
    for (int p = beg; p < end; p += 64) {
        int cnt = end - p;
        if (cnt > 64) cnt = 64;
        int myc = (lane < cnt) ? col[p + lane] : 0;
        int j = 0;
        for (; j + 4 <= cnt; j += 4) {
            int u0 = __shfl(myc, j);
            int u1 = __shfl(myc, j + 1);
            int u2 = __shfl(myc, j + 2);
            int u3 = __shfl(myc, j + 3);
            float2 m0 = __half22float2(hw[(size_t)u0 * 64 + lane]);
            float2 m1 = __half22float2(hw[(size_t)u1 * 64 + lane]);
            float2 m2 = __half22float2(hw[(size_t)u2 * 64 + lane]);
            float2 m3 = __half22float2(hw[(size_t)u3 * 64 + lane]);
            acc.x += (m0.x + m1.x) + (m2.x + m3.x);
            acc.y += (m0.y + m1.y) + (m2.y + m3.y);
        }
        for (; j < cnt; ++j) {
            int u = __shfl(myc, j);
            float2 m = __half22float2(hw[(size_t)u * 64 + lane]);
            acc.x += m.x;
            acc.y += m.y;
        }
    }

    float dvv = dinv[v];
    int c0 = lane * 2;
    float2 g  = *(const float2*)(gamma + c0);
    float2 be = *(const float2*)(beta + c0);
    float2 mn = *(const float2*)(mean + c0);
    float2 va = *(const float2*)(var + c0);
    float2 cb = *(const float2*)(convb + c0);
    float s0 = g.x * rsqrtf(va.x + BN_EPS);
    float s1 = g.y * rsqrtf(va.y + BN_EPS);
    float o0 = (dvv * acc.x + cb.x - mn.x) * s0 + be.x;
    float o1 = (dvv * acc.y + cb.y - mn.y) * s1 + be.y;
    o0 = fmaxf(o0, 0.0f);
    o1 = fmaxf(o1, 0.0f);
    *(float2*)(hout + (size_t)v * 128 + c0) = make_float2(o0, o1);
}

// ---------------- launch ----------------

extern "C" void kernel_launch(void* const* d_in, const int* in_sizes, int n_in,
                              void* d_out, int out_size, void* d_ws, size_t ws_size,
                              hipStream_t stream) {
    const float* x      = (const float*)d_in[0];
    const void*  ei     = d_in[1];
    const float* lin0_w = (const float*)d_in[3];
    const float* lin0_b = (const float*)d_in[4];
    const float* lin1_w = (const float*)d_in[5];
    const float* lin1_b = (const float*)d_in[6];
    const float* conv_w = (const float*)d_in[7];
    const float* conv_b = (const float*)d_in[8];
    const float* bn_g   = (const float*)d_in[9];
    const float* bn_b   = (const float*)d_in[10];
    const float* bn_m   = (const float*)d_in[11];
    const float* bn_v   = (const float*)d_in[12];

    int n = in_sizes[0] / HIDC;   // 100000
    int e = in_sizes[1] / 2;      // 1600000
    int nbk = (n + DPB - 1) / DPB;   // 391

    char* ws = (char*)d_ws;
    size_t off = 0;
    auto alloc = [&](size_t bytes) -> void* {
        void* p = ws + off;
        off += (bytes + 255) & ~(size_t)255;
        return p;
    };
    float*  h      = (float*)alloc((size_t)n * HIDC * 4);
    __half2* hw    = (__half2*)alloc((size_t)n * HIDC * 2);
    int2*   staged = (int2*)alloc((size_t)e * 8);
    int*    col    = (int*)alloc((size_t)e * 4);
    float*  dinv   = (float*)alloc((size_t)n * 4);
    int*    rowptr = (int*)alloc(((size_t)n + 1) * 4);
    int*    bkt    = (int*)alloc((size_t)NBK * 4);
    int*    bbase  = (int*)alloc((size_t)(NBK + 1) * 4);
    int*    bc     = (int*)alloc((size_t)NBK * 4);
    uint4*  wf     = (uint4*)alloc((size_t)5 * 4096 * 16);
    int*    flag   = (int*)alloc(256);

    hipMemsetAsync(bkt, 0, (size_t)NBK * 4, stream);

    detect64<<<1, 64, 0, stream>>>((const unsigned int*)ei, flag);
    pack_w<<<40, 256, 0, stream>>>(lin0_w, conv_w, lin1_w, wf);

    int binb = (e + BIN_CHUNK - 1) / BIN_CHUNK;
    bucket_count<<<binb, 256, 0, stream>>>(ei, flag, bkt, e);
    scan_buckets<<<1, 512, 0, stream>>>(bkt, bbase, bc, rowptr, n, e, nbk);
    bin_pairs<<<binb, 256, 0, stream>>>(ei, flag, bc, staged, e);
    fill_bucket<<<nbk, 256, 0, stream>>>(staged, bbase, dinv, rowptr, col, n);

    int gb = (n + 127) / 128;
    // h = relu(x @ W0 + b0)
    gemm_mfma<<<gb, 512, 0, stream>>>(x, wf, lin0_b, nullptr, h, n, 0);

    for (int l = 0; l < 3; ++l) {
        // hw = dinv * (h @ Wl)   (fp16 message buffer)
        gemm_mfma<<<gb, 512, 0, stream>>>(h, wf + (size_t)(1 + l) * 4096, nullptr, dinv, hw, n, 1);
        int ab = (n + 3) / 4;
        agg_bn_relu<<<ab, 256, 0, stream>>>(hw, rowptr, col, dinv,
                                            conv_b + (size_t)l * HIDC,
                                            bn_g + (size_t)l * HIDC, bn_b + (size_t)l * HIDC,
                                            bn_m + (size_t)l * HIDC, bn_v + (size_t)l * HIDC,
                                            h, n);
    }
    // out = h @ W4 + b4
    gemm_mfma<<<gb, 512, 0, stream>>>(h, wf + (size_t)4 * 4096, lin1_b, nullptr, d_out, n, 2);
}